// Round 16
// baseline (261.258 us; speedup 1.0000x reference)
//
#include <hip/hip_runtime.h>
#include <cstdint>

#define M_PTS 8192
#define N_QRY 8192
#define BATCH 4

typedef unsigned long long ull;

// ---------------- helpers ----------------
__device__ __forceinline__ float d2_exact(float qx, float qy, float qz, float q2, float4 p) {
#pragma clang fp contract(off)
  float dot = (qx * p.x + qy * p.y) + qz * p.z;   // reference op order, no fma
  return (q2 + p.w) - 2.0f * dot;
}

__device__ __forceinline__ unsigned flipf(float d) {
  unsigned u = __float_as_uint(d);
  return u ^ ((unsigned)((int)u >> 31) | 0x80000000u);   // order-preserving float->uint
}

__device__ __forceinline__ int lane_prefix(unsigned long long m) {
  return __builtin_amdgcn_mbcnt_hi((unsigned)(m >> 32),
         __builtin_amdgcn_mbcnt_lo((unsigned)m, 0));
}

__device__ __forceinline__ void ld_lds16(const float4* g, float4* l) {
  __builtin_amdgcn_global_load_lds((const __attribute__((address_space(1))) void*)g,
                                   (__attribute__((address_space(3))) void*)l, 16, 0, 0);
}

// Upper bound on the 16th-smallest of the 64 per-lane mins, via ballot bisection.
// Invariant: count(mn <= hi) >= 16 holds from init (hi = wave max -> 64). 10 steps
// give resolution (hi0-lo0)/1024; looseness only ADDS candidates, never drops one.
__device__ __forceinline__ float tau16(float mn) {
  float lo = mn, hi = mn;
#pragma unroll
  for (int j = 1; j < 64; j <<= 1) {
    lo = fminf(lo, __shfl_xor(lo, j));
    hi = fmaxf(hi, __shfl_xor(hi, j));
  }
#pragma unroll
  for (int it = 0; it < 10; it++) {
    float mid = 0.5f * (lo + hi);
    int cnt = __popcll(__ballot(mn <= mid));
    if (cnt >= 16) hi = mid; else lo = mid;   // wave-uniform
  }
  return hi;
}

// Full 64-lane ascending bitonic sort of u64 keys; lane i ends with the i-th
// smallest. Same network/orientation as the R0-verified rank16.
__device__ __forceinline__ ull bsort64(ull v, int lane) {
#pragma unroll
  for (int k = 2; k <= 64; k <<= 1) {
#pragma unroll
    for (int j = k >> 1; j >= 1; j >>= 1) {
      ull o = __shfl_xor(v, j);
      bool keepmin = (((lane & k) == 0) == ((lane & j) == 0));
      ull lo = v < o ? v : o;
      ull hi = v < o ? o : v;
      v = keepmin ? lo : hi;
    }
  }
  return v;
}

// ---------------- K0: fused prep (pack orig + pack query + transpose lf) ----------
// blocks [0,128): pack original_pts -> pp ; [128,256): pack query_pts -> qp ;
// [256,768): transpose local_feat (B,64,M) -> (B,M,64).
__global__ void prep_kernel(const float* __restrict__ original_pts,
                            const float* __restrict__ query_pts,
                            const float* __restrict__ lf,
                            float4* __restrict__ pp, float4* __restrict__ qp,
                            float* __restrict__ lfT) {
#pragma clang fp contract(off)
  const int bid = blockIdx.x;
  if (bid < 256) {
    const float* src = (bid < 128) ? original_pts : query_pts;
    float4* dst = (bid < 128) ? pp : qp;
    int i = (bid & 127) * 256 + threadIdx.x;     // < 32768
    int b = i >> 13, m = i & (M_PTS - 1);
    const float* s = src + (size_t)b * 3 * M_PTS;
    float x = s[m], y = s[M_PTS + m], z = s[2 * M_PTS + m];
    float ss = (x * x + y * y) + z * z;   // matches jnp.sum(pts**2, axis=1) order
    dst[i] = make_float4(x, y, z, ss);
    return;
  }
  __shared__ float tile[64][65];
  int vbid = bid - 256;
  int bb = vbid >> 7;
  int m0 = (vbid & 127) << 6;
  int tm = threadIdx.x & 63;
  int tc = threadIdx.x >> 6;
  const float* src = lf + (size_t)bb * 64 * M_PTS;
#pragma unroll
  for (int i = 0; i < 16; i++) {
    int ch = i * 4 + tc;
    tile[ch][tm] = src[(size_t)ch * M_PTS + m0 + tm];
  }
  __syncthreads();
  float* dst = lfT + ((size_t)bb * M_PTS + m0) * 64;
#pragma unroll
  for (int i = 0; i < 16; i++) {
    int mm = i * 4 + tc;
    dst[(size_t)mm * 64 + tm] = tile[tm][mm];
  }
}

// ---------------- K1: FUSED knn + feat, 32 queries per 512-thr block ----------------
// R16: R15 structure (4 q/wave via two sequential pair-passes per staged
// chunk — measured clean: VGPR 56, zero spill) with sknn MOVED INTO the
// overlay so total LDS = 40960 B exactly -> 4 blocks/CU (R15's separate
// 2 KB sknn pushed LDS to 43008 -> 3 blocks/CU -> 42% occupancy, which
// cancelled the halved staging/barrier overhead; dur model: generations =
// blocks/resident drops 1.33 -> 1.0). sknn lives at smem+8192 (dead staging
// buffer b1, disjoint from fs scratch at 0-4K); feat PRE-READS the 4 nk's
// into registers (fully unrolled qi loop -> static indices -> VGPRs) before
// the w1T transpose overwrites the region. cand cap stays 192 (full safety
// margin). Algorithm unchanged (R4-lineage tau/finalize/exact-rescore) ->
// output bit-identical.
__global__ void __launch_bounds__(512) fused_kernel(
    const float4* __restrict__ pp, const float4* __restrict__ qp,
    const float* __restrict__ lfT,
    const float* __restrict__ w0, const float* __restrict__ b0,
    const float* __restrict__ g0, const float* __restrict__ be0,
    const float* __restrict__ m0, const float* __restrict__ v0,
    const float* __restrict__ w1, const float* __restrict__ b1,
    const float* __restrict__ g1, const float* __restrict__ be1,
    const float* __restrict__ m1, const float* __restrict__ v1,
    const float* __restrict__ w2, const float* __restrict__ b2,
    float* __restrict__ out) {
  // ---- overlaid LDS (40960 B total = 4 blocks/CU at 512 thr):
  // knn:  b0 8K @0 | b1 8K @8192 | cbuf u32[32][192] 24K @16384
  //       finalize: fs u64 scratch (512 B/wave, 4K) @0 (dead b0);
  //                 sknn int[32][16] 2K @8192 (dead b1)
  // feat: w1T 16.64K @0 | relbuf 2K @16640 | f0v 8K @18688 | outbuf 8.45K @26880
  __shared__ __align__(16) char smem[40960];
  const int tid = threadIdx.x;
  const int lane = tid & 63;
  const int wave = tid >> 6;                      // 0..7
  const int gq0 = blockIdx.x * 32;                // block's 32 queries
  const int qa = gq0 + wave * 4;                  // this wave's four queries
  const int b = gq0 >> 13;                        // 256 blocks per batch
  const float4* pb = pp + ((size_t)b << 13);

  // ================= PHASE 1: exact KNN top-16 (R4-lineage) =================
  {
    unsigned (*cbuf)[192] = (unsigned(*)[192])(smem + 16384);

    float axA, ayA, azA, axB, ayB, azB, axC, ayC, azC, axD, ayD, azD;
    {
      float4 A4 = qp[qa + 0], B4 = qp[qa + 1], C4 = qp[qa + 2], D4 = qp[qa + 3];
      axA = -2.0f * A4.x; ayA = -2.0f * A4.y; azA = -2.0f * A4.z;
      axB = -2.0f * B4.x; ayB = -2.0f * B4.y; azB = -2.0f * B4.z;
      axC = -2.0f * C4.x; ayC = -2.0f * C4.y; azC = -2.0f * C4.z;
      axD = -2.0f * D4.x; ayD = -2.0f * D4.y; azD = -2.0f * D4.z;
    }
    int cntA = 0, cntB = 0, cntC = 0, cntD = 0;
    unsigned* cqA = cbuf[wave * 4 + 0];
    unsigned* cqB = cbuf[wave * 4 + 1];
    unsigned* cqC = cbuf[wave * 4 + 2];
    unsigned* cqD = cbuf[wave * 4 + 3];

    float mnA = 3.402823466e38f, mnB = mnA, mnC = mnA, mnD = mnA;
    float tauA = 0.0f, tauB = 0.0f, tauC = 0.0f, tauD = 0.0f;

    auto bufp = [&](int d) -> float4* {           // pointer ARITHMETIC, not
      return (float4*)(smem + ((size_t)d << 13)); // runtime-indexed array
    };

    auto stage = [&](int d, int s) {
      // 8 waves x 64 lanes cover the 512-pt sub-chunk with ONE ld_lds16 each
      const float4* g = pb + s * 512 + wave * 64 + lane;
      ld_lds16(g, bufp(d) + wave * 64);   // wave-uniform LDS base + lane*16
    };

    auto minpair = [&](const float4* sp,
                       float ax0, float ay0, float az0,
                       float ax1, float ay1, float az1,
                       float& m0r, float& m1r) {
#pragma unroll
      for (int j = 0; j < 8; j++) {
        float4 p = sp[j * 64 + lane];
        m0r = fminf(m0r, __builtin_fmaf(ax0, p.x, __builtin_fmaf(ay0, p.y,
                         __builtin_fmaf(az0, p.z, p.w))));
        m1r = fminf(m1r, __builtin_fmaf(ax1, p.x, __builtin_fmaf(ay1, p.y,
                         __builtin_fmaf(az1, p.z, p.w))));
      }
    };

    auto collect = [&](float e, float tau, unsigned* cq, int& cnt, unsigned idx) {
      bool pred = e <= tau;
      unsigned long long mask = __ballot(pred);
      if (mask) {                         // wave-uniform; most iters skip here
        int pos = cnt + lane_prefix(mask);
        if (pred && pos < 192) cq[pos] = idx;
        cnt += __popcll(mask);
      }
    };

    auto fusedpair = [&](const float4* sp, unsigned base,
                         float ax0, float ay0, float az0,
                         float ax1, float ay1, float az1,
                         float& m0r, float& m1r, float t0, float t1,
                         unsigned* c0, unsigned* c1, int& n0, int& n1) {
#pragma unroll
      for (int j = 0; j < 8; j++) {
        float4 p = sp[j * 64 + lane];
        float e0 = __builtin_fmaf(ax0, p.x, __builtin_fmaf(ay0, p.y,
                   __builtin_fmaf(az0, p.z, p.w)));
        float e1 = __builtin_fmaf(ax1, p.x, __builtin_fmaf(ay1, p.y,
                   __builtin_fmaf(az1, p.z, p.w)));
        m0r = fminf(m0r, e0);
        m1r = fminf(m1r, e1);
        unsigned idx = base + j * 64 + lane;
        collect(e0, t0, c0, n0, idx);
        collect(e1, t1, c1, n1, idx);
      }
    };

    // ---- prologue: seed tau on first 1024 pts (two-pass over sc0/sc1) ----
    stage(0, 0);
    __syncthreads();                     // sc0 visible
    stage(1, 1);                         // sc1 in flight during min passes
    minpair(bufp(0), axA, ayA, azA, axB, ayB, azB, mnA, mnB);
    minpair(bufp(0), axC, ayC, azC, axD, ayD, azD, mnC, mnD);
    __syncthreads();                     // sc1 visible
    minpair(bufp(1), axA, ayA, azA, axB, ayB, azB, mnA, mnB);
    minpair(bufp(1), axC, ayC, azC, axD, ayD, azD, mnC, mnD);
    tauA = tau16(mnA) + 0.01f;           // margin >> fma-vs-exact divergence
    tauB = tau16(mnB) + 0.01f;
    tauC = tau16(mnC) + 0.01f;
    tauD = tau16(mnD) + 0.01f;
    fusedpair(bufp(0), 0,   axA, ayA, azA, axB, ayB, azB, mnA, mnB, tauA, tauB, cqA, cqB, cntA, cntB);
    fusedpair(bufp(0), 0,   axC, ayC, azC, axD, ayD, azD, mnC, mnD, tauC, tauD, cqC, cqD, cntC, cntD);
    fusedpair(bufp(1), 512, axA, ayA, azA, axB, ayB, azB, mnA, mnB, tauA, tauB, cqA, cqB, cntA, cntB);
    fusedpair(bufp(1), 512, axC, ayC, azC, axD, ayD, azD, mnC, mnD, tauC, tauD, cqC, cqD, cntC, cntD);
    __syncthreads();                     // all waves done reading sc0/sc1
    stage(0, 2);
    __syncthreads();                     // sc2 visible (single true stall)

    // ---- steady state: stage next sub-chunk, compute current (2 passes), barrier ----
    for (int s = 2; s < 16; ++s) {
      if (s < 15) stage((s + 1) & 1, s + 1);
      const float4* sp = bufp(s & 1);
      unsigned base = (unsigned)(s * 512);
      fusedpair(sp, base, axA, ayA, azA, axB, ayB, azB, mnA, mnB, tauA, tauB, cqA, cqB, cntA, cntB);
      fusedpair(sp, base, axC, ayC, azC, axD, ayD, azD, mnC, mnD, tauC, tauD, cqC, cqD, cntC, cntD);
      if (s == 3 || s == 7 || s == 11) { // tighten tau at 2048/4096/6144 prefixes
        tauA = fminf(tauA, tau16(mnA) + 0.01f);
        tauB = fminf(tauB, tau16(mnB) + 0.01f);
        tauC = fminf(tauC, tau16(mnC) + 0.01f);
        tauD = fminf(tauD, tau16(mnD) + 0.01f);
      }
      __syncthreads();                   // drains vmcnt -> next buffer visible;
    }                                    // also protects the swap

    // staging buffers now dead: fs scratch overlays b0, sknn overlays b1
    ull* fs = (ull*)(smem + wave * 512); // 64 entries/wave, 8 waves = 4 KB

    auto finalize = [&](unsigned* cu, int cnt, int* srow, int gq) {
      float4 q4 = qp[gq];                     // reload (L2-hit), not parked
      float qx = q4.x, qy = q4.y, qz = q4.z, q2 = q4.w;
      int E = cnt < 192 ? cnt : 192;          // E >= 16 guaranteed by prologue tau
      unsigned i0 = (lane < E) ? cu[lane] : 0u;
      unsigned i1 = (lane + 64 < E) ? cu[lane + 64] : 0u;
      unsigned i2 = (lane + 128 < E) ? cu[lane + 128] : 0u;
      float4 p0 = pb[i0];                     // parallel L2-hit loads
      float4 p1 = pb[i1];
      float4 p2 = pb[i2];
      ull k0 = ~0ull, k1 = ~0ull, k2 = ~0ull;
      if (lane < E)
        k0 = ((ull)flipf(d2_exact(qx, qy, qz, q2, p0)) << 32) | i0;
      if (lane + 64 < E)
        k1 = ((ull)flipf(d2_exact(qx, qy, qz, q2, p1)) << 32) | i1;
      if (lane + 128 < E)
        k2 = ((ull)flipf(d2_exact(qx, qy, qz, q2, p2)) << 32) | i2;
      // lane-min, then T = 16th-smallest lane-min (E>=16 -> lanes 0..15 all
      // hold a real k0). Every true top-16 key <= T; keys <= T live only in
      // the 16 lanes whose lane-min <= T -> at most 48 survivors.
      ull ml = k0 < k1 ? k0 : k1;
      if (k2 < ml) ml = k2;
      ull T = __shfl(bsort64(ml, lane), 15);
      int c2 = 0;
      {
        bool pr = k0 <= T; ull m = __ballot(pr);
        int pos = c2 + lane_prefix(m);
        if (pr) fs[pos] = k0;
        c2 += __popcll(m);
      }
      {
        bool pr = k1 <= T; ull m = __ballot(pr);
        int pos = c2 + lane_prefix(m);
        if (pr) fs[pos] = k1;
        c2 += __popcll(m);
      }
      {
        bool pr = k2 <= T; ull m = __ballot(pr);
        int pos = c2 + lane_prefix(m);
        if (pr) fs[pos] = k2;
        c2 += __popcll(m);
      }
      // wave-local RAW: lgkmcnt ordering suffices, no barrier
      ull kk = (lane < c2) ? fs[lane] : ~0ull;
      ull fin = bsort64(kk, lane);
      if (lane < 16) srow[lane] = (int)(unsigned)fin;   // -> LDS (dead b1)
    };

    int* sknn_s = (int*)(smem + 8192);   // 32 rows x 16 ints, wave-local rows
    finalize(cqA, cntA, sknn_s + (wave * 4 + 0) * 16, qa + 0);
    finalize(cqB, cntB, sknn_s + (wave * 4 + 1) * 16, qa + 1);
    finalize(cqC, cntC, sknn_s + (wave * 4 + 2) * 16, qa + 2);
    finalize(cqD, cntD, sknn_s + (wave * 4 + 3) * 16, qa + 3);
  }

  // pre-read this wave's 4 nk values into REGISTERS before the w1T transpose
  // overwrites the sknn region (wave-local RAW: lgkmcnt ordering suffices)
  int nkq[4];
  {
    const int* sknn_s = (const int*)(smem + 8192);
#pragma unroll
    for (int qi = 0; qi < 4; qi++)
      nkq[qi] = sknn_s[(wave * 4 + qi) * 16 + (lane & 15)];
  }
  __syncthreads();                       // all nk reads done; smem reusable

  // ================= PHASE 2: feature pipeline (R8/R11 body, 4 q/wave) =================
  float (*w1T)[65]     = (float(*)[65])smem;
  float4 (*relbuf)[16] = (float4(*)[16])(smem + 16640);
  float4 (*f0v)[64]    = (float4(*)[64])(smem + 18688);
  float (*outbuf)[33]  = (float(*)[33])(smem + 26880);

  // cooperative transpose of w1 (64x64) into LDS: 512 threads x 2 float4
  {
    const float4* w1f4 = (const float4*)w1;
#pragma unroll
    for (int k = 0; k < 2; k++) {
      int linear4 = tid + k * 512;           // float4 index in [0,1024)
      int c = linear4 >> 4;                  // row (out channel)
      int c2 = (linear4 & 15) * 4;           // col (in channel)
      float4 t = w1f4[linear4];
      w1T[c2 + 0][c] = t.x;
      w1T[c2 + 1][c] = t.y;
      w1T[c2 + 2][c] = t.z;
      w1T[c2 + 3][c] = t.w;
    }
  }

  // BN folds (inline; fp order matches R0's fold_kernel)
  const float inv0 = g0[lane] / sqrtf(v0[lane] + 1e-5f);
  const float w00 = w0[lane * 3 + 0] * inv0;
  const float w01 = w0[lane * 3 + 1] * inv0;
  const float w02 = w0[lane * 3 + 2] * inv0;
  const float bb0 = (b0[lane] - m0[lane]) * inv0 + be0[lane];
  const float inv1 = g1[lane] / sqrtf(v1[lane] + 1e-5f);
  const float bb1 = (b1[lane] - m1[lane]) * inv1 + be1[lane];

  const float w2a = w2[lane], w2b = w2[64 + lane];
  const float bias2 = b2[0];
  const float* lfb = lfT + (((size_t)b << 13)) * 64;

  __syncthreads();                       // w1T visible to all waves

#pragma unroll
  for (int qi = 0; qi < 4; qi++) {       // full unroll -> nkq[qi] is static
    const int gq = qa + qi;
    const float4 q4 = qp[gq];
    int nk = nkq[qi];
    float4 pk = pb[nk];
    // issue the lfb gathers NOW (they only need nk); latency hides under
    // conv0 + matvec below
    int i0 = __shfl(nk, 0), i1 = __shfl(nk, 1), i2 = __shfl(nk, 2), i3 = __shfl(nk, 3);
    float p0 = lfb[(size_t)i0 * 64 + lane];
    float p1 = lfb[(size_t)i1 * 64 + lane];
    float p2 = lfb[(size_t)i2 * 64 + lane];
    float p3 = lfb[(size_t)i3 * 64 + lane];

    if (lane < 16)
      relbuf[wave][lane] = make_float4(pk.x - q4.x, pk.y - q4.y, pk.z - q4.z, 0.0f);
    // wave-local RAW: lgkmcnt ordering suffices, no barrier

    float g = 0.0f, f0 = 0, f1 = 0, f2 = 0, f3 = 0;
#pragma unroll
    for (int k = 0; k < 16; k++) {
      float4 r = relbuf[wave][k];
      float y = fmaxf(0.0f, w00 * r.x + w01 * r.y + w02 * r.z + bb0);
      g = fmaxf(g, y);
      if (k == 0) f0 = y; else if (k == 1) f1 = y;
      else if (k == 2) f2 = y; else if (k == 3) f3 = y;
    }
    f0v[wave][lane] = make_float4(f0, f1, f2, f3);

    float a0 = 0, a1 = 0, a2 = 0, a3 = 0;
#pragma unroll
    for (int c2 = 0; c2 < 64; c2++) {
      float w = w1T[c2][lane];           // LDS, lane-consecutive: conflict-free
      float4 fb = f0v[wave][c2];         // LDS broadcast (same addr all lanes)
      a0 = fmaf(w, fb.x, a0); a1 = fmaf(w, fb.y, a1);
      a2 = fmaf(w, fb.z, a2); a3 = fmaf(w, fb.w, a3);
    }
    float r0 = fmaxf(0.0f, fmaf(a0, inv1, bb1));
    float r1 = fmaxf(0.0f, fmaf(a1, inv1, bb1));
    float r2 = fmaxf(0.0f, fmaf(a2, inv1, bb1));
    float r3 = fmaxf(0.0f, fmaf(a3, inv1, bb1));

    float s0 = w2a * r0, s1 = w2a * r1, s2 = w2a * r2, s3 = w2a * r3, tg = w2b * g;
#pragma unroll
    for (int j = 1; j < 64; j <<= 1) {
      s0 += __shfl_xor(s0, j);
      s1 += __shfl_xor(s1, j);
      s2 += __shfl_xor(s2, j);
      s3 += __shfl_xor(s3, j);
      tg += __shfl_xor(tg, j);
    }
    float wk0 = 1.0f / (1.0f + __expf(-(s0 + tg + bias2)));
    float wk1 = 1.0f / (1.0f + __expf(-(s1 + tg + bias2)));
    float wk2 = 1.0f / (1.0f + __expf(-(s2 + tg + bias2)));
    float wk3 = 1.0f / (1.0f + __expf(-(s3 + tg + bias2)));

    float oc = ((1.0f - wk0) * r0 + wk0 * p0)
             + ((1.0f - wk1) * r1 + wk1 * p1)
             + ((1.0f - wk2) * r2 + wk2 * p2)
             + ((1.0f - wk3) * r3 + wk3 * p3);
    outbuf[lane][wave * 4 + qi] = oc;
  }
  __syncthreads();

  // coalesced output: thread t -> channel c = t>>3, 8 query-groups via float4
  {
    int c = tid >> 3, j = tid & 7;
    float4 o4 = make_float4(outbuf[c][j * 4 + 0], outbuf[c][j * 4 + 1],
                            outbuf[c][j * 4 + 2], outbuf[c][j * 4 + 3]);
    *(float4*)(out + (((size_t)(b * 64 + c)) << 13) + (gq0 & (N_QRY - 1)) + j * 4) = o4;
  }
}

extern "C" void kernel_launch(void* const* d_in, const int* in_sizes, int n_in,
                              void* d_out, int out_size, void* d_ws, size_t ws_size,
                              hipStream_t stream) {
  (void)in_sizes; (void)n_in; (void)out_size; (void)ws_size;
  const float* original_pts = (const float*)d_in[0];
  const float* query_pts   = (const float*)d_in[1];
  const float* local_feat  = (const float*)d_in[2];
  const float* w0 = (const float*)d_in[3];
  const float* b0 = (const float*)d_in[4];
  const float* g0 = (const float*)d_in[5];
  const float* be0 = (const float*)d_in[6];
  const float* m0 = (const float*)d_in[7];
  const float* v0 = (const float*)d_in[8];
  const float* w1 = (const float*)d_in[9];
  const float* b1 = (const float*)d_in[10];
  const float* g1 = (const float*)d_in[11];
  const float* be1 = (const float*)d_in[12];
  const float* m1 = (const float*)d_in[13];
  const float* v1 = (const float*)d_in[14];
  const float* w2 = (const float*)d_in[15];
  const float* b2 = (const float*)d_in[16];
  float* out = (float*)d_out;

  // workspace layout (16B aligned): pp 512K, qp 512K, lfT 8M
  char* ws = (char*)d_ws;
  float4* pp  = (float4*)(ws);                 // 512 KB
  float4* qp  = (float4*)(ws + 524288);        // 512 KB
  float*  lfT = (float*)(ws + 1048576);        // 8 MB

  prep_kernel<<<768, 256, 0, stream>>>(original_pts, query_pts, local_feat,
                                       pp, qp, lfT);
  fused_kernel<<<1024, 512, 0, stream>>>(pp, qp, lfT,
                                         w0, b0, g0, be0, m0, v0,
                                         w1, b1, g1, be1, m1, v1,
                                         w2, b2, out);
}

// Round 18
// 247.118 us; speedup vs baseline: 1.0572x; 1.0572x over previous
//
#include <hip/hip_runtime.h>
#include <cstdint>

#define M_PTS 8192
#define N_QRY 8192
#define BATCH 4

typedef unsigned long long ull;

// ---------------- helpers ----------------
__device__ __forceinline__ float d2_exact(float qx, float qy, float qz, float q2, float4 p) {
#pragma clang fp contract(off)
  float dot = (qx * p.x + qy * p.y) + qz * p.z;   // reference op order, no fma
  return (q2 + p.w) - 2.0f * dot;
}

__device__ __forceinline__ unsigned flipf(float d) {
  unsigned u = __float_as_uint(d);
  return u ^ ((unsigned)((int)u >> 31) | 0x80000000u);   // order-preserving float->uint
}

__device__ __forceinline__ int lane_prefix(unsigned long long m) {
  return __builtin_amdgcn_mbcnt_hi((unsigned)(m >> 32),
         __builtin_amdgcn_mbcnt_lo((unsigned)m, 0));
}

__device__ __forceinline__ void ld_lds16(const float4* g, float4* l) {
  __builtin_amdgcn_global_load_lds((const __attribute__((address_space(1))) void*)g,
                                   (__attribute__((address_space(3))) void*)l, 16, 0, 0);
}

// Upper bound on the 16th-smallest of the 64 per-lane mins, via ballot bisection.
// Invariant: count(mn <= hi) >= 16 holds from init (hi = wave max -> 64). 10 steps
// give resolution (hi0-lo0)/1024; looseness only ADDS candidates, never drops one.
__device__ __forceinline__ float tau16(float mn) {
  float lo = mn, hi = mn;
#pragma unroll
  for (int j = 1; j < 64; j <<= 1) {
    lo = fminf(lo, __shfl_xor(lo, j));
    hi = fmaxf(hi, __shfl_xor(hi, j));
  }
#pragma unroll
  for (int it = 0; it < 10; it++) {
    float mid = 0.5f * (lo + hi);
    int cnt = __popcll(__ballot(mn <= mid));
    if (cnt >= 16) hi = mid; else lo = mid;   // wave-uniform
  }
  return hi;
}

// Full 64-lane ascending bitonic sort of u64 keys; lane i ends with the i-th
// smallest. Same network/orientation as the R0-verified rank16.
__device__ __forceinline__ ull bsort64(ull v, int lane) {
#pragma unroll
  for (int k = 2; k <= 64; k <<= 1) {
#pragma unroll
    for (int j = k >> 1; j >= 1; j >>= 1) {
      ull o = __shfl_xor(v, j);
      bool keepmin = (((lane & k) == 0) == ((lane & j) == 0));
      ull lo = v < o ? v : o;
      ull hi = v < o ? o : v;
      v = keepmin ? lo : hi;
    }
  }
  return v;
}

// ---------------- K0: fused prep (pack orig + pack query + transpose lf) ----------
// blocks [0,128): pack original_pts -> pp ; [128,256): pack query_pts -> qp ;
// [256,768): transpose local_feat (B,64,M) -> (B,M,64).
__global__ void prep_kernel(const float* __restrict__ original_pts,
                            const float* __restrict__ query_pts,
                            const float* __restrict__ lf,
                            float4* __restrict__ pp, float4* __restrict__ qp,
                            float* __restrict__ lfT) {
#pragma clang fp contract(off)
  const int bid = blockIdx.x;
  if (bid < 256) {
    const float* src = (bid < 128) ? original_pts : query_pts;
    float4* dst = (bid < 128) ? pp : qp;
    int i = (bid & 127) * 256 + threadIdx.x;     // < 32768
    int b = i >> 13, m = i & (M_PTS - 1);
    const float* s = src + (size_t)b * 3 * M_PTS;
    float x = s[m], y = s[M_PTS + m], z = s[2 * M_PTS + m];
    float ss = (x * x + y * y) + z * z;   // matches jnp.sum(pts**2, axis=1) order
    dst[i] = make_float4(x, y, z, ss);
    return;
  }
  __shared__ float tile[64][65];
  int vbid = bid - 256;
  int bb = vbid >> 7;
  int m0 = (vbid & 127) << 6;
  int tm = threadIdx.x & 63;
  int tc = threadIdx.x >> 6;
  const float* src = lf + (size_t)bb * 64 * M_PTS;
#pragma unroll
  for (int i = 0; i < 16; i++) {
    int ch = i * 4 + tc;
    tile[ch][tm] = src[(size_t)ch * M_PTS + m0 + tm];
  }
  __syncthreads();
  float* dst = lfT + ((size_t)bb * M_PTS + m0) * 64;
#pragma unroll
  for (int i = 0; i < 16; i++) {
    int mm = i * 4 + tc;
    dst[(size_t)mm * 64 + tm] = tile[tm][mm];
  }
}

// ---------------- K1: FUSED knn + feat, 16 queries per 512-thr block ----------------
// R18: byte-exact revert to R13 — the best PASSING configuration (245.0 us
// total; fused 186 us, VGPR 40, LDS 32256, zero spill, occupancy 62%).
// R17's sub-exact-fit LDS variant (4 blocks/CU) failed the post-timing
// replay check nondeterministically; no provable mechanism found, so the
// scheduling-sensitive variant is disqualified. Geometry arms all measured:
// R14 (1024 thr) +42us, R15 (4 q/wave) +-0, R16 (exact-fit 40960) +-0,
// R17 (39936) FAIL. R13 is the verified local optimum of this family.
__global__ void __launch_bounds__(512) fused_kernel(
    const float4* __restrict__ pp, const float4* __restrict__ qp,
    const float* __restrict__ lfT,
    const float* __restrict__ w0, const float* __restrict__ b0,
    const float* __restrict__ g0, const float* __restrict__ be0,
    const float* __restrict__ m0, const float* __restrict__ v0,
    const float* __restrict__ w1, const float* __restrict__ b1,
    const float* __restrict__ g1, const float* __restrict__ be1,
    const float* __restrict__ m1, const float* __restrict__ v1,
    const float* __restrict__ w2, const float* __restrict__ b2,
    float* __restrict__ out) {
  // ---- overlaid LDS: knn {spts 16K @0, cbuf 12K @16384} / feat {w1T 16.64K
  // @0, relbuf 2K @16640, f0v 8K @18688, outbuf 4.35K @26880} ----
  __shared__ __align__(16) char smem[31232];
  __shared__ int sknn[16][16];           // persists across the phase boundary
  const int tid = threadIdx.x;
  const int lane = tid & 63;
  const int wave = tid >> 6;                      // 0..7
  const int gq0 = blockIdx.x * 16;                // block's 16 queries
  const int qa = gq0 + wave * 2;                  // this wave's two queries
  const int b = qa >> 13;                         // 512 blocks per batch
  const float4* pb = pp + ((size_t)b << 13);

  // ================= PHASE 1: exact KNN top-16 (R4-lineage) =================
  {
    ull (*cbuf)[96] = (ull(*)[96])(smem + 16384);

    const float4 A4 = qp[qa];
    const float4 B4 = qp[qa + 1];
    const float axA = -2.0f * A4.x, ayA = -2.0f * A4.y, azA = -2.0f * A4.z;
    const float axB = -2.0f * B4.x, ayB = -2.0f * B4.y, azB = -2.0f * B4.z;

    int cntA = 0, cntB = 0;
    unsigned* cqA = (unsigned*)cbuf[wave * 2 + 0];
    unsigned* cqB = (unsigned*)cbuf[wave * 2 + 1];

    float mnA = 3.402823466e38f, mnB = 3.402823466e38f;
    float tauA = 0.0f, tauB = 0.0f;

    auto bufp = [&](int d) -> float4* {           // pointer ARITHMETIC, not
      return (float4*)(smem + ((size_t)d << 13)); // runtime-indexed array
    };

    auto stage = [&](int d, int s) {
      // 8 waves x 64 lanes cover the 512-pt sub-chunk with ONE ld_lds16 each
      const float4* g = pb + s * 512 + wave * 64 + lane;
      ld_lds16(g, bufp(d) + wave * 64);   // wave-uniform LDS base + lane*16
    };

    auto minpass = [&](const float4* sp) {
#pragma unroll
      for (int j = 0; j < 8; j++) {
        float4 p = sp[j * 64 + lane];
        mnA = fminf(mnA, __builtin_fmaf(axA, p.x, __builtin_fmaf(ayA, p.y,
                         __builtin_fmaf(azA, p.z, p.w))));
        mnB = fminf(mnB, __builtin_fmaf(axB, p.x, __builtin_fmaf(ayB, p.y,
                         __builtin_fmaf(azB, p.z, p.w))));
      }
    };

    auto collect = [&](float e, float tau, unsigned* cq, int& cnt, unsigned idx) {
      bool pred = e <= tau;
      unsigned long long mask = __ballot(pred);
      if (mask) {                         // wave-uniform; most iters skip here
        int pos = cnt + lane_prefix(mask);
        if (pred && pos < 192) cq[pos] = idx;
        cnt += __popcll(mask);
      }
    };

    auto fused = [&](const float4* sp, unsigned base) {
#pragma unroll
      for (int j = 0; j < 8; j++) {
        float4 p = sp[j * 64 + lane];
        float ea = __builtin_fmaf(axA, p.x, __builtin_fmaf(ayA, p.y,
                   __builtin_fmaf(azA, p.z, p.w)));
        float eb = __builtin_fmaf(axB, p.x, __builtin_fmaf(ayB, p.y,
                   __builtin_fmaf(azB, p.z, p.w)));
        mnA = fminf(mnA, ea);
        mnB = fminf(mnB, eb);
        unsigned idx = base + j * 64 + lane;
        collect(ea, tauA, cqA, cntA, idx);
        collect(eb, tauB, cqB, cntB, idx);
      }
    };

    // ---- prologue: seed tau on first 1024 pts (two-pass over sc0/sc1) ----
    stage(0, 0);
    __syncthreads();                     // sc0 visible
    stage(1, 1);                         // in flight during minpass(sc0)
    minpass(bufp(0));
    __syncthreads();                     // sc1 visible
    minpass(bufp(1));
    tauA = tau16(mnA) + 0.01f;           // margin >> fma-vs-exact divergence
    tauB = tau16(mnB) + 0.01f;
    fused(bufp(0), 0);
    fused(bufp(1), 512);
    __syncthreads();                     // all waves done reading sc0/sc1
    stage(0, 2);
    __syncthreads();                     // sc2 visible (single true stall)

    // ---- steady state: stage next sub-chunk, compute current, barrier ----
    for (int s = 2; s < 16; ++s) {
      if (s < 15) stage((s + 1) & 1, s + 1);
      fused(bufp(s & 1), (unsigned)(s * 512));
      if (s == 3 || s == 7 || s == 11) { // tighten tau at 2048/4096/6144 prefixes
        tauA = fminf(tauA, tau16(mnA) + 0.01f);
        tauB = fminf(tauB, tau16(mnB) + 0.01f);
      }
      __syncthreads();                   // drains vmcnt -> next buffer visible;
    }                                    // also protects the swap

    auto finalize = [&](ull* cb, int cnt, int* srow,
                        float qx, float qy, float qz, float q2) {
      unsigned* cu = (unsigned*)cb;
      int E = cnt < 192 ? cnt : 192;          // E >= 16 guaranteed by prologue tau
      unsigned i0 = (lane < E) ? cu[lane] : 0u;
      unsigned i1 = (lane + 64 < E) ? cu[lane + 64] : 0u;
      unsigned i2 = (lane + 128 < E) ? cu[lane + 128] : 0u;
      float4 p0 = pb[i0];                     // parallel L2-hit loads
      float4 p1 = pb[i1];
      float4 p2 = pb[i2];
      ull k0 = ~0ull, k1 = ~0ull, k2 = ~0ull;
      if (lane < E)
        k0 = ((ull)flipf(d2_exact(qx, qy, qz, q2, p0)) << 32) | i0;
      if (lane + 64 < E)
        k1 = ((ull)flipf(d2_exact(qx, qy, qz, q2, p1)) << 32) | i1;
      if (lane + 128 < E)
        k2 = ((ull)flipf(d2_exact(qx, qy, qz, q2, p2)) << 32) | i2;
      // lane-min, then T = 16th-smallest lane-min (E>=16 -> lanes 0..15 all
      // hold a real k0). Every true top-16 key <= T; keys <= T live only in
      // the 16 lanes whose lane-min <= T -> at most 48 survivors.
      ull ml = k0 < k1 ? k0 : k1;
      if (k2 < ml) ml = k2;
      ull T = __shfl(bsort64(ml, lane), 15);
      int c2 = 0;
      {
        bool pr = k0 <= T; ull m = __ballot(pr);
        int pos = c2 + lane_prefix(m);
        if (pr) cb[pos] = k0;
        c2 += __popcll(m);
      }
      {
        bool pr = k1 <= T; ull m = __ballot(pr);
        int pos = c2 + lane_prefix(m);
        if (pr) cb[pos] = k1;
        c2 += __popcll(m);
      }
      {
        bool pr = k2 <= T; ull m = __ballot(pr);
        int pos = c2 + lane_prefix(m);
        if (pr) cb[pos] = k2;
        c2 += __popcll(m);
      }
      // wave-local RAW: lgkmcnt ordering suffices, no barrier
      ull kk = (lane < c2) ? cb[lane] : ~0ull;
      ull fin = bsort64(kk, lane);
      if (lane < 16) srow[lane] = (int)(unsigned)fin;   // -> LDS, not global
    };

    finalize(cbuf[wave * 2 + 0], cntA, sknn[wave * 2 + 0], A4.x, A4.y, A4.z, A4.w);
    finalize(cbuf[wave * 2 + 1], cntB, sknn[wave * 2 + 1], B4.x, B4.y, B4.z, B4.w);
  }

  __syncthreads();                       // all finalize done; smem reusable

  // ================= PHASE 2: feature pipeline (R8/R11 body) =================
  float (*w1T)[65]    = (float(*)[65])smem;
  float4 (*relbuf)[16] = (float4(*)[16])(smem + 16640);
  float4 (*f0v)[64]   = (float4(*)[64])(smem + 18688);
  float (*outbuf)[17] = (float(*)[17])(smem + 26880);

  // cooperative transpose of w1 (64x64) into LDS: 512 threads x 2 float4
  {
    const float4* w1f4 = (const float4*)w1;
#pragma unroll
    for (int k = 0; k < 2; k++) {
      int linear4 = tid + k * 512;           // float4 index in [0,1024)
      int c = linear4 >> 4;                  // row (out channel)
      int c2 = (linear4 & 15) * 4;           // col (in channel)
      float4 t = w1f4[linear4];
      w1T[c2 + 0][c] = t.x;
      w1T[c2 + 1][c] = t.y;
      w1T[c2 + 2][c] = t.z;
      w1T[c2 + 3][c] = t.w;
    }
  }

  // BN folds (inline; fp order matches R0's fold_kernel)
  const float inv0 = g0[lane] / sqrtf(v0[lane] + 1e-5f);
  const float w00 = w0[lane * 3 + 0] * inv0;
  const float w01 = w0[lane * 3 + 1] * inv0;
  const float w02 = w0[lane * 3 + 2] * inv0;
  const float bb0 = (b0[lane] - m0[lane]) * inv0 + be0[lane];
  const float inv1 = g1[lane] / sqrtf(v1[lane] + 1e-5f);
  const float bb1 = (b1[lane] - m1[lane]) * inv1 + be1[lane];

  const float w2a = w2[lane], w2b = w2[64 + lane];
  const float bias2 = b2[0];
  const float* lfb = lfT + (((size_t)b << 13)) * 64;

  __syncthreads();                       // w1T visible to all waves

  for (int qi = 0; qi < 2; qi++) {
    const int gq = qa + qi;
    const float4 q4 = qp[gq];
    int nk = sknn[wave * 2 + qi][lane & 15];   // LDS broadcast read
    float4 pk = pb[nk];
    // issue the lfb gathers NOW (they only need nk); latency hides under
    // conv0 + matvec below
    int i0 = __shfl(nk, 0), i1 = __shfl(nk, 1), i2 = __shfl(nk, 2), i3 = __shfl(nk, 3);
    float p0 = lfb[(size_t)i0 * 64 + lane];
    float p1 = lfb[(size_t)i1 * 64 + lane];
    float p2 = lfb[(size_t)i2 * 64 + lane];
    float p3 = lfb[(size_t)i3 * 64 + lane];

    if (lane < 16)
      relbuf[wave][lane] = make_float4(pk.x - q4.x, pk.y - q4.y, pk.z - q4.z, 0.0f);
    // wave-local RAW: lgkmcnt ordering suffices, no barrier

    float g = 0.0f, f0 = 0, f1 = 0, f2 = 0, f3 = 0;
#pragma unroll
    for (int k = 0; k < 16; k++) {
      float4 r = relbuf[wave][k];
      float y = fmaxf(0.0f, w00 * r.x + w01 * r.y + w02 * r.z + bb0);
      g = fmaxf(g, y);
      if (k == 0) f0 = y; else if (k == 1) f1 = y;
      else if (k == 2) f2 = y; else if (k == 3) f3 = y;
    }
    f0v[wave][lane] = make_float4(f0, f1, f2, f3);

    float a0 = 0, a1 = 0, a2 = 0, a3 = 0;
#pragma unroll
    for (int c2 = 0; c2 < 64; c2++) {
      float w = w1T[c2][lane];           // LDS, lane-consecutive: conflict-free
      float4 fb = f0v[wave][c2];         // LDS broadcast (same addr all lanes)
      a0 = fmaf(w, fb.x, a0); a1 = fmaf(w, fb.y, a1);
      a2 = fmaf(w, fb.z, a2); a3 = fmaf(w, fb.w, a3);
    }
    float r0 = fmaxf(0.0f, fmaf(a0, inv1, bb1));
    float r1 = fmaxf(0.0f, fmaf(a1, inv1, bb1));
    float r2 = fmaxf(0.0f, fmaf(a2, inv1, bb1));
    float r3 = fmaxf(0.0f, fmaf(a3, inv1, bb1));

    float s0 = w2a * r0, s1 = w2a * r1, s2 = w2a * r2, s3 = w2a * r3, tg = w2b * g;
#pragma unroll
    for (int j = 1; j < 64; j <<= 1) {
      s0 += __shfl_xor(s0, j);
      s1 += __shfl_xor(s1, j);
      s2 += __shfl_xor(s2, j);
      s3 += __shfl_xor(s3, j);
      tg += __shfl_xor(tg, j);
    }
    float wk0 = 1.0f / (1.0f + __expf(-(s0 + tg + bias2)));
    float wk1 = 1.0f / (1.0f + __expf(-(s1 + tg + bias2)));
    float wk2 = 1.0f / (1.0f + __expf(-(s2 + tg + bias2)));
    float wk3 = 1.0f / (1.0f + __expf(-(s3 + tg + bias2)));

    float oc = ((1.0f - wk0) * r0 + wk0 * p0)
             + ((1.0f - wk1) * r1 + wk1 * p1)
             + ((1.0f - wk2) * r2 + wk2 * p2)
             + ((1.0f - wk3) * r3 + wk3 * p3);
    outbuf[lane][wave * 2 + qi] = oc;
  }
  __syncthreads();

  // coalesced output: thread t<256 -> channel c = t>>2, 4 queries via float4
  if (tid < 256) {
    int c = tid >> 2, j = tid & 3;
    float4 o4 = make_float4(outbuf[c][j * 4 + 0], outbuf[c][j * 4 + 1],
                            outbuf[c][j * 4 + 2], outbuf[c][j * 4 + 3]);
    *(float4*)(out + (((size_t)(b * 64 + c)) << 13) + (gq0 & (N_QRY - 1)) + j * 4) = o4;
  }
}

extern "C" void kernel_launch(void* const* d_in, const int* in_sizes, int n_in,
                              void* d_out, int out_size, void* d_ws, size_t ws_size,
                              hipStream_t stream) {
  (void)in_sizes; (void)n_in; (void)out_size; (void)ws_size;
  const float* original_pts = (const float*)d_in[0];
  const float* query_pts   = (const float*)d_in[1];
  const float* local_feat  = (const float*)d_in[2];
  const float* w0 = (const float*)d_in[3];
  const float* b0 = (const float*)d_in[4];
  const float* g0 = (const float*)d_in[5];
  const float* be0 = (const float*)d_in[6];
  const float* m0 = (const float*)d_in[7];
  const float* v0 = (const float*)d_in[8];
  const float* w1 = (const float*)d_in[9];
  const float* b1 = (const float*)d_in[10];
  const float* g1 = (const float*)d_in[11];
  const float* be1 = (const float*)d_in[12];
  const float* m1 = (const float*)d_in[13];
  const float* v1 = (const float*)d_in[14];
  const float* w2 = (const float*)d_in[15];
  const float* b2 = (const float*)d_in[16];
  float* out = (float*)d_out;

  // workspace layout (16B aligned): pp 512K, qp 512K, lfT 8M
  char* ws = (char*)d_ws;
  float4* pp  = (float4*)(ws);                 // 512 KB
  float4* qp  = (float4*)(ws + 524288);        // 512 KB
  float*  lfT = (float*)(ws + 1048576);        // 8 MB

  prep_kernel<<<768, 256, 0, stream>>>(original_pts, query_pts, local_feat,
                                       pp, qp, lfT);
  fused_kernel<<<2048, 512, 0, stream>>>(pp, qp, lfT,
                                         w0, b0, g0, be0, m0, v0,
                                         w1, b1, g1, be1, m1, v1,
                                         w2, b2, out);
}